// Round 11
// baseline (330.055 us; speedup 1.0000x reference)
//
#include <hip/hip_runtime.h>

typedef unsigned short u16;
typedef __bf16 bf16x8 __attribute__((ext_vector_type(8)));
typedef float f32x4 __attribute__((ext_vector_type(4)));

#define Bb 4
#define Tt 2048
#define Cc 1024

#define GLOAD_LDS16(g, l)                                                     \
  __builtin_amdgcn_global_load_lds(                                           \
      (const __attribute__((address_space(1))) void*)(g),                     \
      (__attribute__((address_space(3))) void*)(l), 16, 0, 0)

#define WAITV10 asm volatile("s_waitcnt vmcnt(10)" ::: "memory")
#define WAITV8 asm volatile("s_waitcnt vmcnt(8)" ::: "memory")
#define WAITV0 asm volatile("s_waitcnt vmcnt(0)" ::: "memory")

__device__ inline u16 f2bf(float f) {
  unsigned u = __builtin_bit_cast(unsigned, f);
  unsigned r = u + 0x7fffu + ((u >> 16) & 1u);
  return (u16)(r >> 16);
}

// ---------------- cast x -> bf16 (vectorized) ----------------
__global__ __launch_bounds__(256) void cast_f32_bf16_vec4(
    const float* __restrict__ in, u16* __restrict__ out, int n4) {
  int i = blockIdx.x * 256 + threadIdx.x;
  if (i >= n4) return;
  float4 v = reinterpret_cast<const float4*>(in)[i];
  ushort4 o;
  o.x = f2bf(v.x); o.y = f2bf(v.y); o.z = f2bf(v.z); o.w = f2bf(v.w);
  reinterpret_cast<ushort4*>(out)[i] = o;
}

// ---------------- zero rowsum buffer (graph-safe init) ----------------
__global__ __launch_bounds__(256) void zero_f32(float* __restrict__ p, int n) {
  int i = blockIdx.x * 256 + threadIdx.x;
  if (i < n) p[i] = 0.f;
}

// ---------------- transpose-cast W[1024][3072] -> Wt[3072][1024] bf16 ----------------
__global__ __launch_bounds__(256) void transpose_cast_w(
    const float* __restrict__ W, u16* __restrict__ Wt) {
  __shared__ float tile[32][33];
  int n0 = blockIdx.x * 32;
  int k0 = blockIdx.y * 32;
  int tx = threadIdx.x;
  int ty = threadIdx.y;
#pragma unroll
  for (int i = 0; i < 4; i++)
    tile[ty + i * 8][tx] = W[(size_t)(k0 + ty + i * 8) * 3072 + n0 + tx];
  __syncthreads();
#pragma unroll
  for (int i = 0; i < 4; i++)
    Wt[(size_t)(n0 + ty + i * 8) * 1024 + k0 + tx] = f2bf(tile[tx][ty + i * 8]);
}

// ---- shared swizzle helpers (T2 st-swizzle, 3-bit row-pair involution) ----
__device__ __forceinline__ void stage_unitA(const u16* __restrict__ G,
                                            u16* lds_unit, int tid) {
#pragma unroll
  for (int j = 0; j < 2; j++) {                  // 16 KB unit, 512 threads
    int u = j * 8192 + tid * 16;
    int l = u ^ (((u >> 7) & 7) << 4);
    GLOAD_LDS16(G + (size_t)(l >> 6) * Cc + ((l & 63) >> 1), lds_unit + (u >> 1));
  }
}
__device__ __forceinline__ void stage_unitB3(const u16* __restrict__ G,
                                             u16* lds_unit, int tid) {
#pragma unroll
  for (int j = 0; j < 3; j++) {                  // 24 KB unit, 512 threads
    int u = j * 8192 + tid * 16;
    int l = u ^ (((u >> 7) & 7) << 4);
    GLOAD_LDS16(G + (size_t)(l >> 6) * Cc + ((l & 63) >> 1), lds_unit + (u >> 1));
  }
}

__device__ __forceinline__ bf16x8 lds_frag(const u16* unit, int row, int fq) {
  int off = row * 64 + fq * 16;
  off ^= ((off >> 7) & 7) << 4;
  return *reinterpret_cast<const bf16x8*>(
      reinterpret_cast<const char*>(unit) + off);
}

// ============ QKV GEMM: 256x384 tile, 8-phase schedule, EXACT 256-block fill ============
// Grid (8,32) = 256 blocks = 1 block/CU, one perfectly balanced round.
// 8 waves (2M x 4N), wave tile 128x96, acc[8][6], 24 MFMA/phase.
// LDS: A 2kh x 2par x 16KB + B 2kh x 2par x 24KB = 160 KiB (full pool).
// vmcnt ledger: units alternate 2/3 loads; steady-state WAITV(10) leaves the
// 4 newest units (2+3+2+3) in flight, forces the 2 units needed next phase.
__global__ __launch_bounds__(512, 1) void gemm_qkv_384(
    const u16* __restrict__ A0, const u16* __restrict__ B0,
    u16* __restrict__ qO, u16* __restrict__ kO, u16* __restrict__ vTO) {
  const int NT = Cc / 64;  // 16
  int bx = blockIdx.x, by = blockIdx.y;
  const u16* A = A0 + (size_t)by * 256 * Cc;
  const u16* Bt = B0 + (size_t)bx * 384 * Cc;

  __shared__ __attribute__((aligned(16))) u16 ldsA[2][2][8192];   // [kh][par] 64 KiB
  __shared__ __attribute__((aligned(16))) u16 ldsB[2][2][12288];  // [kh][par] 96 KiB

  int tid = threadIdx.x;
  int lane = tid & 63, w = tid >> 6;
  int wm = (w >> 2) * 128, wn = (w & 3) * 96;
  int fr = lane & 15, fq = lane >> 4;

  f32x4 acc[8][6] = {};

  // prologue: A0kh0,B0kh0, A0kh1,B0kh1, A1kh0,B1kh0  (15 loads)
  stage_unitA(A + 0, &ldsA[0][0][0], tid);
  stage_unitB3(Bt + 0, &ldsB[0][0][0], tid);
  stage_unitA(A + 32, &ldsA[1][0][0], tid);
  stage_unitB3(Bt + 32, &ldsB[1][0][0], tid);
  stage_unitA(A + 64, &ldsA[0][1][0], tid);
  stage_unitB3(Bt + 64, &ldsB[0][1][0], tid);
  WAITV10;  // first 5 loads (A0kh0 + B0kh0) landed
  __builtin_amdgcn_s_barrier();

  for (int t = 0; t < NT; ++t) {
    int par = t & 1, parn = par ^ 1;
    bool st1 = (t + 1 < NT);
    bool st2 = (t + 2 < NT);
    bool tail = (t >= NT - 2);
    bf16x8 a[4], b[6];

    // phase 1: (mh=0, kh=0)
#pragma unroll
    for (int mi = 0; mi < 4; mi++)
      a[mi] = lds_frag(&ldsA[0][par][0], wm + mi * 16 + fr, fq);
#pragma unroll
    for (int ni = 0; ni < 6; ni++)
      b[ni] = lds_frag(&ldsB[0][par][0], wn + ni * 16 + fr, fq);
    if (st1) stage_unitA(A + (t + 1) * 64 + 32, &ldsA[1][parn][0], tid);
    __builtin_amdgcn_s_barrier();
    __builtin_amdgcn_s_setprio(1);
#pragma unroll
    for (int mi = 0; mi < 4; mi++)
#pragma unroll
      for (int ni = 0; ni < 6; ni++)
        acc[mi][ni] = __builtin_amdgcn_mfma_f32_16x16x32_bf16(a[mi], b[ni], acc[mi][ni], 0, 0, 0);
    __builtin_amdgcn_s_setprio(0);
    __builtin_amdgcn_s_barrier();

    // phase 2: (mh=1, kh=0) — reuse b
#pragma unroll
    for (int mi = 0; mi < 4; mi++)
      a[mi] = lds_frag(&ldsA[0][par][0], wm + 64 + mi * 16 + fr, fq);
    if (st1) stage_unitB3(Bt + (t + 1) * 64 + 32, &ldsB[1][parn][0], tid);
    __builtin_amdgcn_s_barrier();
    __builtin_amdgcn_s_setprio(1);
#pragma unroll
    for (int mi = 0; mi < 4; mi++)
#pragma unroll
      for (int ni = 0; ni < 6; ni++)
        acc[4 + mi][ni] = __builtin_amdgcn_mfma_f32_16x16x32_bf16(a[mi], b[ni], acc[4 + mi][ni], 0, 0, 0);
    __builtin_amdgcn_s_setprio(0);
    if (tail) { WAITV0; } else { WAITV10; }  // kh1(t) units now required
    __builtin_amdgcn_s_barrier();

    // phase 3: (mh=0, kh=1)
#pragma unroll
    for (int mi = 0; mi < 4; mi++)
      a[mi] = lds_frag(&ldsA[1][par][0], wm + mi * 16 + fr, fq);
#pragma unroll
    for (int ni = 0; ni < 6; ni++)
      b[ni] = lds_frag(&ldsB[1][par][0], wn + ni * 16 + fr, fq);
    if (st2) stage_unitA(A + (t + 2) * 64, &ldsA[0][par][0], tid);
    __builtin_amdgcn_s_barrier();
    __builtin_amdgcn_s_setprio(1);
#pragma unroll
    for (int mi = 0; mi < 4; mi++)
#pragma unroll
      for (int ni = 0; ni < 6; ni++)
        acc[mi][ni] = __builtin_amdgcn_mfma_f32_16x16x32_bf16(a[mi], b[ni], acc[mi][ni], 0, 0, 0);
    __builtin_amdgcn_s_setprio(0);
    __builtin_amdgcn_s_barrier();

    // phase 4: (mh=1, kh=1) — reuse b
#pragma unroll
    for (int mi = 0; mi < 4; mi++)
      a[mi] = lds_frag(&ldsA[1][par][0], wm + 64 + mi * 16 + fr, fq);
    if (st2) stage_unitB3(Bt + (t + 2) * 64, &ldsB[0][par][0], tid);
    __builtin_amdgcn_s_barrier();
    __builtin_amdgcn_s_setprio(1);
#pragma unroll
    for (int mi = 0; mi < 4; mi++)
#pragma unroll
      for (int ni = 0; ni < 6; ni++)
        acc[4 + mi][ni] = __builtin_amdgcn_mfma_f32_16x16x32_bf16(a[mi], b[ni], acc[4 + mi][ni], 0, 0, 0);
    __builtin_amdgcn_s_setprio(0);
    if (tail) { WAITV0; } else { WAITV10; }  // kh0(t+1) units now required
    __builtin_amdgcn_s_barrier();
  }

  // epilogue: scatter q, k, vT
#pragma unroll
  for (int mi = 0; mi < 8; mi++) {
#pragma unroll
    for (int ni = 0; ni < 6; ni++) {
#pragma unroll
      for (int r = 0; r < 4; r++) {
        int m = by * 256 + wm + mi * 16 + fq * 4 + r;
        int n = bx * 384 + wn + ni * 16 + fr;
        u16 hv = f2bf(acc[mi][ni][r]);
        int seg = n >> 10, cn = n & 1023;
        int b = m >> 11, tt = m & 2047;
        if (seg == 0)
          qO[(((size_t)(b * Tt + tt)) << 10) + cn] = hv;
        else if (seg == 1)
          kO[(((size_t)(b * Tt + tt)) << 10) + cn] = hv;
        else
          vTO[((size_t)(b * Cc + cn)) * Tt + tt] = hv;
      }
    }
  }
}

// ---- 512-thread stage helper for the 256-wide E kernel ----
__device__ __forceinline__ void stage_unit(const u16* __restrict__ G, int ld,
                                           u16* lds_unit, int tid) {
#pragma unroll
  for (int j = 0; j < 2; j++) {
    int u = j * 8192 + tid * 16;
    int l = u ^ (((u >> 7) & 7) << 4);
    GLOAD_LDS16(G + (size_t)(l >> 6) * ld + ((l & 63) >> 1), lds_unit + (u >> 1));
  }
}

// ============ 256x256 8-phase GEMM — fused score+exp (E = exp(q.k^T/32), rowsum) ============
__global__ __launch_bounds__(512, 2) void gemm256_e(
    const u16* __restrict__ A0, const u16* __restrict__ B0,
    size_t sAbatch, size_t sBbatch,
    u16* __restrict__ EO, float* __restrict__ rowsum) {
  const int lda = Cc, ldb = Cc, NT = Cc / 64;  // 16
  int bx = blockIdx.x, by = blockIdx.y, bz = blockIdx.z;
  if (bx > by) return;

  const u16* A = A0 + (size_t)bz * sAbatch + (size_t)by * 256 * lda;
  const u16* Bt = B0 + (size_t)bz * sBbatch + (size_t)bx * 256 * ldb;

  __shared__ __attribute__((aligned(16))) u16 lds[4][2][8192];  // 128 KiB

  int tid = threadIdx.x;
  int lane = tid & 63, w = tid >> 6;
  int wm = (w >> 2) * 128, wn = (w & 3) * 64;
  int fr = lane & 15, fq = lane >> 4;

  f32x4 acc[8][4] = {};

  stage_unit(A + 0, lda, &lds[0][0][0], tid);
  stage_unit(Bt + 0, ldb, &lds[2][0][0], tid);
  stage_unit(A + 32, lda, &lds[1][0][0], tid);
  stage_unit(Bt + 32, ldb, &lds[3][0][0], tid);
  stage_unit(A + 64, lda, &lds[0][1][0], tid);
  stage_unit(Bt + 64, ldb, &lds[2][1][0], tid);
  WAITV8;
  __builtin_amdgcn_s_barrier();

  for (int t = 0; t < NT; ++t) {
    int par = t & 1;
    int parn = par ^ 1;
    bool st1 = (t + 1 < NT);
    bool st2 = (t + 2 < NT);
    bool tail = (t >= NT - 2);
    bf16x8 a[4], b[4];

    // phase 1: (mh=0, kh=0)
#pragma unroll
    for (int mi = 0; mi < 4; mi++)
      a[mi] = lds_frag(&lds[0][par][0], wm + mi * 16 + fr, fq);
#pragma unroll
    for (int ni = 0; ni < 4; ni++)
      b[ni] = lds_frag(&lds[2][par][0], wn + ni * 16 + fr, fq);
    if (st1) stage_unit(A + (t + 1) * 64 + 32, lda, &lds[1][parn][0], tid);
    __builtin_amdgcn_s_barrier();
    __builtin_amdgcn_s_setprio(1);
#pragma unroll
    for (int mi = 0; mi < 4; mi++)
#pragma unroll
      for (int ni = 0; ni < 4; ni++)
        acc[mi][ni] = __builtin_amdgcn_mfma_f32_16x16x32_bf16(a[mi], b[ni], acc[mi][ni], 0, 0, 0);
    __builtin_amdgcn_s_setprio(0);
    __builtin_amdgcn_s_barrier();

    // phase 2: (mh=1, kh=0)
#pragma unroll
    for (int mi = 0; mi < 4; mi++)
      a[mi] = lds_frag(&lds[0][par][0], wm + 64 + mi * 16 + fr, fq);
    if (st1) stage_unit(Bt + (t + 1) * 64 + 32, ldb, &lds[3][parn][0], tid);
    __builtin_amdgcn_s_barrier();
    __builtin_amdgcn_s_setprio(1);
#pragma unroll
    for (int mi = 0; mi < 4; mi++)
#pragma unroll
      for (int ni = 0; ni < 4; ni++)
        acc[4 + mi][ni] = __builtin_amdgcn_mfma_f32_16x16x32_bf16(a[mi], b[ni], acc[4 + mi][ni], 0, 0, 0);
    __builtin_amdgcn_s_setprio(0);
    if (tail) { WAITV0; } else { WAITV8; }
    __builtin_amdgcn_s_barrier();

    // phase 3: (mh=0, kh=1)
#pragma unroll
    for (int mi = 0; mi < 4; mi++)
      a[mi] = lds_frag(&lds[1][par][0], wm + mi * 16 + fr, fq);
#pragma unroll
    for (int ni = 0; ni < 4; ni++)
      b[ni] = lds_frag(&lds[3][par][0], wn + ni * 16 + fr, fq);
    if (st2) stage_unit(A + (t + 2) * 64, lda, &lds[0][par][0], tid);
    __builtin_amdgcn_s_barrier();
    __builtin_amdgcn_s_setprio(1);
#pragma unroll
    for (int mi = 0; mi < 4; mi++)
#pragma unroll
      for (int ni = 0; ni < 4; ni++)
        acc[mi][ni] = __builtin_amdgcn_mfma_f32_16x16x32_bf16(a[mi], b[ni], acc[mi][ni], 0, 0, 0);
    __builtin_amdgcn_s_setprio(0);
    __builtin_amdgcn_s_barrier();

    // phase 4: (mh=1, kh=1)
#pragma unroll
    for (int mi = 0; mi < 4; mi++)
      a[mi] = lds_frag(&lds[1][par][0], wm + 64 + mi * 16 + fr, fq);
    if (st2) stage_unit(Bt + (t + 2) * 64, ldb, &lds[2][par][0], tid);
    __builtin_amdgcn_s_barrier();
    __builtin_amdgcn_s_setprio(1);
#pragma unroll
    for (int mi = 0; mi < 4; mi++)
#pragma unroll
      for (int ni = 0; ni < 4; ni++)
        acc[4 + mi][ni] = __builtin_amdgcn_mfma_f32_16x16x32_bf16(a[mi], b[ni], acc[4 + mi][ni], 0, 0, 0);
    __builtin_amdgcn_s_setprio(0);
    if (tail) { WAITV0; } else { WAITV8; }
    __builtin_amdgcn_s_barrier();
  }

  // epilogue: fused exp + causal mask + bf16 E write + per-row partial sums
  {
    float rpart[8][4];
#pragma unroll
    for (int mi = 0; mi < 8; mi++)
#pragma unroll
      for (int r = 0; r < 4; r++) rpart[mi][r] = 0.f;
#pragma unroll
    for (int mi = 0; mi < 8; mi++) {
#pragma unroll
      for (int ni = 0; ni < 4; ni++) {
#pragma unroll
        for (int r = 0; r < 4; r++) {
          int m = by * 256 + wm + mi * 16 + fq * 4 + r;
          int n = bx * 256 + wn + ni * 16 + fr;
          float e = 0.f;
          if (n <= m) e = __expf(fminf(acc[mi][ni][r] * 0.03125f, 30.f));
          EO[((size_t)bz * Tt + m) * Tt + n] = f2bf(e);
          rpart[mi][r] += e;
        }
      }
    }
#pragma unroll
    for (int mi = 0; mi < 8; mi++) {
#pragma unroll
      for (int r = 0; r < 4; r++) {
        float v = rpart[mi][r];
        v += __shfl_xor(v, 1);
        v += __shfl_xor(v, 2);
        v += __shfl_xor(v, 4);
        v += __shfl_xor(v, 8);
        if (fr == 0) {
          int m = by * 256 + wm + mi * 16 + fq * 4 + r;
          atomicAdd(&rowsum[(size_t)bz * Tt + m], v);
        }
      }
    }
  }
}

// ---------------- m97-structure B^T MFMA GEMM, 128x128 tile, 4 waves ----------------
// Y = E.vT / rowsum (fp32 out), causal K truncation
__global__ __launch_bounds__(256) void gemm_bt_pv(
    const u16* __restrict__ A0, const u16* __restrict__ B0,
    size_t sAbatch, size_t sBbatch,
    int K, int lda, int ldb, const float* __restrict__ rowsum,
    float* __restrict__ YO) {
  int bx = blockIdx.x, by = blockIdx.y, bz = blockIdx.z;

  const u16* A = A0 + (size_t)bz * sAbatch + (size_t)by * 128 * lda;
  const u16* Bt = B0 + (size_t)bz * sBbatch + (size_t)bx * 128 * ldb;
  int kEnd = min(K, (by + 1) * 128);

  __shared__ __attribute__((aligned(16))) u16 As[128 * 32];
  __shared__ __attribute__((aligned(16))) u16 Bs[128 * 32];

  int tid = threadIdx.x;
  int lane = tid & 63, w = tid >> 6;
  int wr = (w >> 1) * 64, wc = (w & 1) * 64;
  int row16 = lane & 15, kq = (lane >> 4) * 8;

  int r0 = w * 16 + (lane >> 2);
  int c0 = (lane & 3) * 8;

  f32x4 acc[4][4] = {};

  for (int kt = 0; kt < kEnd; kt += 32) {
    const u16* Ag = A + (size_t)r0 * lda + kt + c0;
    const u16* Bg = Bt + (size_t)r0 * ldb + kt + c0;
    GLOAD_LDS16(Ag, &As[w * 512]);
    GLOAD_LDS16(Ag + (size_t)64 * lda, &As[2048 + w * 512]);
    GLOAD_LDS16(Bg, &Bs[w * 512]);
    GLOAD_LDS16(Bg + (size_t)64 * ldb, &Bs[2048 + w * 512]);
    __syncthreads();

    bf16x8 a[4], b[4];
#pragma unroll
    for (int m = 0; m < 4; m++)
      a[m] = *reinterpret_cast<const bf16x8*>(&As[(wr + m * 16 + row16) * 32 + kq]);
#pragma unroll
    for (int n = 0; n < 4; n++)
      b[n] = *reinterpret_cast<const bf16x8*>(&Bs[(wc + n * 16 + row16) * 32 + kq]);
#pragma unroll
    for (int m = 0; m < 4; m++)
#pragma unroll
      for (int n = 0; n < 4; n++)
        acc[m][n] = __builtin_amdgcn_mfma_f32_16x16x32_bf16(a[m], b[n], acc[m][n], 0, 0, 0);
    __syncthreads();
  }

  int colf = lane & 15, rbase = (lane >> 4) * 4;
#pragma unroll
  for (int i = 0; i < 4; i++) {
#pragma unroll
    for (int r = 0; r < 4; r++) {
      int m = by * 128 + wr + i * 16 + rbase + r;
      float inv = 1.0f / rowsum[(size_t)bz * Tt + m];
#pragma unroll
      for (int j = 0; j < 4; j++) {
        int n = bx * 128 + wc + j * 16 + colf;
        YO[((size_t)bz * Tt + m) * Cc + n] = acc[i][j][r] * inv;
      }
    }
  }
}

extern "C" void kernel_launch(void* const* d_in, const int* in_sizes, int n_in,
                              void* d_out, int out_size, void* d_ws, size_t ws_size,
                              hipStream_t stream) {
  const float* x = (const float*)d_in[0];
  const float* W = (const float*)d_in[1];
  float* Y = (float*)d_out;

  char* ws = (char*)d_ws;
  size_t off = 0;
  auto carve = [&](size_t bytes) -> void* {
    void* p = ws + off;
    off += (bytes + 255) & ~(size_t)255;
    return p;
  };
  u16* xb = (u16*)carve((size_t)Bb * Tt * Cc * 2);
  u16* wt = (u16*)carve((size_t)3 * Cc * Cc * 2);
  u16* qb = (u16*)carve((size_t)Bb * Tt * Cc * 2);
  u16* kb = (u16*)carve((size_t)Bb * Tt * Cc * 2);
  u16* vT = (u16*)carve((size_t)Bb * Cc * Tt * 2);
  u16* E = (u16*)carve((size_t)Bb * Tt * Tt * 2);   // exp(scores) bf16
  float* rowsum = (float*)carve((size_t)Bb * Tt * 4);

  cast_f32_bf16_vec4<<<(Bb * Tt * Cc / 4 + 255) / 256, 256, 0, stream>>>(
      x, xb, Bb * Tt * Cc / 4);
  zero_f32<<<(Bb * Tt + 255) / 256, 256, 0, stream>>>(rowsum, Bb * Tt);
  transpose_cast_w<<<dim3(96, 32), dim3(32, 8), 0, stream>>>(W, wt);
  // qkv projection: 256x384 tiles, 8-phase, exactly 256 blocks (1 balanced round)
  gemm_qkv_384<<<dim3(8, 32), 512, 0, stream>>>(xb, wt, qb, kb, vT);
  // E = exp(q k^T / 32) + rowsum: 256^2 8-phase, causal tri-grid
  gemm256_e<<<dim3(8, 8, 4), 512, 0, stream>>>(
      qb, kb, (size_t)Tt * Cc, (size_t)Tt * Cc, E, rowsum);
  // Y = (E v) / rowsum (causal K truncation), 128^2 m97 structure
  gemm_bt_pv<<<dim3(8, 16, 4), 256, 0, stream>>>(
      E, vT, (size_t)Tt * Tt, (size_t)Cc * Tt, Tt, Tt, Tt, rowsum, Y);
}

// Round 12
// 278.595 us; speedup vs baseline: 1.1847x; 1.1847x over previous
//
#include <hip/hip_runtime.h>

typedef unsigned short u16;
typedef __bf16 bf16x8 __attribute__((ext_vector_type(8)));
typedef float f32x4 __attribute__((ext_vector_type(4)));

#define Bb 4
#define Tt 2048
#define Cc 1024

#define GLOAD_LDS16(g, l)                                                     \
  __builtin_amdgcn_global_load_lds(                                           \
      (const __attribute__((address_space(1))) void*)(g),                     \
      (__attribute__((address_space(3))) void*)(l), 16, 0, 0)

#define WAITV10 asm volatile("s_waitcnt vmcnt(10)" ::: "memory")
#define WAITV8 asm volatile("s_waitcnt vmcnt(8)" ::: "memory")
#define WAITV0 asm volatile("s_waitcnt vmcnt(0)" ::: "memory")

__device__ inline u16 f2bf(float f) {
  unsigned u = __builtin_bit_cast(unsigned, f);
  unsigned r = u + 0x7fffu + ((u >> 16) & 1u);
  return (u16)(r >> 16);
}

// ---------------- cast x -> bf16 (vectorized) ----------------
__global__ __launch_bounds__(256) void cast_f32_bf16_vec4(
    const float* __restrict__ in, u16* __restrict__ out, int n4) {
  int i = blockIdx.x * 256 + threadIdx.x;
  if (i >= n4) return;
  float4 v = reinterpret_cast<const float4*>(in)[i];
  ushort4 o;
  o.x = f2bf(v.x); o.y = f2bf(v.y); o.z = f2bf(v.z); o.w = f2bf(v.w);
  reinterpret_cast<ushort4*>(out)[i] = o;
}

// ---------------- zero rowsum buffer (graph-safe init) ----------------
__global__ __launch_bounds__(256) void zero_f32(float* __restrict__ p, int n) {
  int i = blockIdx.x * 256 + threadIdx.x;
  if (i < n) p[i] = 0.f;
}

// ---------------- transpose-cast W[1024][3072] -> Wt[3072][1024] bf16 ----------------
__global__ __launch_bounds__(256) void transpose_cast_w(
    const float* __restrict__ W, u16* __restrict__ Wt) {
  __shared__ float tile[32][33];
  int n0 = blockIdx.x * 32;
  int k0 = blockIdx.y * 32;
  int tx = threadIdx.x;
  int ty = threadIdx.y;
#pragma unroll
  for (int i = 0; i < 4; i++)
    tile[ty + i * 8][tx] = W[(size_t)(k0 + ty + i * 8) * 3072 + n0 + tx];
  __syncthreads();
#pragma unroll
  for (int i = 0; i < 4; i++)
    Wt[(size_t)(n0 + ty + i * 8) * 1024 + k0 + tx] = f2bf(tile[tx][ty + i * 8]);
}

// ---- T2 st-swizzle (3-bit row-pair involution), fragment reader ----
__device__ __forceinline__ bf16x8 lds_frag(const u16* unit, int row, int fq) {
  int off = row * 64 + fq * 16;
  off ^= ((off >> 7) & 7) << 4;
  return *reinterpret_cast<const bf16x8*>(
      reinterpret_cast<const char*>(unit) + off);
}

// 256-thread stagers: A unit 8 KB (128x32), B unit 12 KB (192x32)
__device__ __forceinline__ void stageA2_256(const u16* __restrict__ G,
                                            u16* unit, int tid) {
#pragma unroll
  for (int j = 0; j < 2; j++) {
    int u = j * 4096 + tid * 16;
    int l = u ^ (((u >> 7) & 7) << 4);
    GLOAD_LDS16(G + (size_t)(l >> 6) * Cc + ((l & 63) >> 1), unit + (u >> 1));
  }
}
__device__ __forceinline__ void stageB3_256(const u16* __restrict__ G,
                                            u16* unit, int tid) {
#pragma unroll
  for (int j = 0; j < 3; j++) {
    int u = j * 4096 + tid * 16;
    int l = u ^ (((u >> 7) & 7) << 4);
    GLOAD_LDS16(G + (size_t)(l >> 6) * Cc + ((l & 63) >> 1), unit + (u >> 1));
  }
}

// ============ QKV GEMM: 128x192 tile, 8-phase counted-vmcnt, 2 blocks/CU ============
// Grid (16,64) = 1024 blocks = 2 co-resident/CU x 256 CUs x 2 balanced rounds.
// 4 waves (2M x 2N), wave tile 64x96, acc[4][6] = 96 VGPR (no spill; R11 lesson).
// LDS: A 2kh x 2par x 8KB + B 2kh x 2par x 12KB = 80 KiB (exactly 2/CU).
// Wait structure identical to R11's HW-validated ledger: units alternate 2/3
// loads; WAITV10 at phases 2/4 leaves the 4 newest units (2+3+2+3) in flight.
__global__ __launch_bounds__(256, 2) void gemm_qkv_128x192(
    const u16* __restrict__ A0, const u16* __restrict__ B0,
    u16* __restrict__ qO, u16* __restrict__ kO, u16* __restrict__ vTO) {
  const int NT = Cc / 64;  // 16
  int bx = blockIdx.x, by = blockIdx.y;
  const u16* A = A0 + (size_t)by * 128 * Cc;
  const u16* Bt = B0 + (size_t)bx * 192 * Cc;

  __shared__ __attribute__((aligned(16))) u16 ldsA[2][2][4096];  // [kh][par] 32 KiB
  __shared__ __attribute__((aligned(16))) u16 ldsB[2][2][6144];  // [kh][par] 48 KiB

  int tid = threadIdx.x;
  int lane = tid & 63, w = tid >> 6;
  int wm = (w >> 1) * 64, wn = (w & 1) * 96;
  int fr = lane & 15, fq = lane >> 4;

  f32x4 acc[4][6] = {};

  // prologue: A0k0(2), B0k0(3), A0k1(2), B0k1(3), A1k0(2), B1k0(3) = 15 loads
  stageA2_256(A + 0, &ldsA[0][0][0], tid);
  stageB3_256(Bt + 0, &ldsB[0][0][0], tid);
  stageA2_256(A + 32, &ldsA[1][0][0], tid);
  stageB3_256(Bt + 32, &ldsB[1][0][0], tid);
  stageA2_256(A + 64, &ldsA[0][1][0], tid);
  stageB3_256(Bt + 64, &ldsB[0][1][0], tid);
  WAITV10;  // first 5 loads (A0k0 + B0k0) landed
  __builtin_amdgcn_s_barrier();

  for (int t = 0; t < NT; ++t) {
    int par = t & 1, parn = par ^ 1;
    bool st1 = (t + 1 < NT);
    bool st2 = (t + 2 < NT);
    bool tail = (t >= NT - 2);
    bf16x8 a[2], b[6];

    // phase 1: (mh=0, kh=0)
#pragma unroll
    for (int mi = 0; mi < 2; mi++)
      a[mi] = lds_frag(&ldsA[0][par][0], wm + mi * 16 + fr, fq);
#pragma unroll
    for (int ni = 0; ni < 6; ni++)
      b[ni] = lds_frag(&ldsB[0][par][0], wn + ni * 16 + fr, fq);
    if (st1) stageA2_256(A + (t + 1) * 64 + 32, &ldsA[1][parn][0], tid);
    __builtin_amdgcn_s_barrier();
    __builtin_amdgcn_s_setprio(1);
#pragma unroll
    for (int mi = 0; mi < 2; mi++)
#pragma unroll
      for (int ni = 0; ni < 6; ni++)
        acc[mi][ni] = __builtin_amdgcn_mfma_f32_16x16x32_bf16(a[mi], b[ni], acc[mi][ni], 0, 0, 0);
    __builtin_amdgcn_s_setprio(0);
    __builtin_amdgcn_s_barrier();

    // phase 2: (mh=1, kh=0) — reuse b
#pragma unroll
    for (int mi = 0; mi < 2; mi++)
      a[mi] = lds_frag(&ldsA[0][par][0], wm + 32 + mi * 16 + fr, fq);
    if (st1) stageB3_256(Bt + (t + 1) * 64 + 32, &ldsB[1][parn][0], tid);
    __builtin_amdgcn_s_barrier();
    __builtin_amdgcn_s_setprio(1);
#pragma unroll
    for (int mi = 0; mi < 2; mi++)
#pragma unroll
      for (int ni = 0; ni < 6; ni++)
        acc[2 + mi][ni] = __builtin_amdgcn_mfma_f32_16x16x32_bf16(a[mi], b[ni], acc[2 + mi][ni], 0, 0, 0);
    __builtin_amdgcn_s_setprio(0);
    if (tail) { WAITV0; } else { WAITV10; }  // kh1(t) units now required
    __builtin_amdgcn_s_barrier();

    // phase 3: (mh=0, kh=1)
#pragma unroll
    for (int mi = 0; mi < 2; mi++)
      a[mi] = lds_frag(&ldsA[1][par][0], wm + mi * 16 + fr, fq);
#pragma unroll
    for (int ni = 0; ni < 6; ni++)
      b[ni] = lds_frag(&ldsB[1][par][0], wn + ni * 16 + fr, fq);
    if (st2) stageA2_256(A + (t + 2) * 64, &ldsA[0][par][0], tid);
    __builtin_amdgcn_s_barrier();
    __builtin_amdgcn_s_setprio(1);
#pragma unroll
    for (int mi = 0; mi < 2; mi++)
#pragma unroll
      for (int ni = 0; ni < 6; ni++)
        acc[mi][ni] = __builtin_amdgcn_mfma_f32_16x16x32_bf16(a[mi], b[ni], acc[mi][ni], 0, 0, 0);
    __builtin_amdgcn_s_setprio(0);
    __builtin_amdgcn_s_barrier();

    // phase 4: (mh=1, kh=1) — reuse b
#pragma unroll
    for (int mi = 0; mi < 2; mi++)
      a[mi] = lds_frag(&ldsA[1][par][0], wm + 32 + mi * 16 + fr, fq);
    if (st2) stageB3_256(Bt + (t + 2) * 64, &ldsB[0][par][0], tid);
    __builtin_amdgcn_s_barrier();
    __builtin_amdgcn_s_setprio(1);
#pragma unroll
    for (int mi = 0; mi < 2; mi++)
#pragma unroll
      for (int ni = 0; ni < 6; ni++)
        acc[2 + mi][ni] = __builtin_amdgcn_mfma_f32_16x16x32_bf16(a[mi], b[ni], acc[2 + mi][ni], 0, 0, 0);
    __builtin_amdgcn_s_setprio(0);
    if (tail) { WAITV0; } else { WAITV10; }  // kh0(t+1) units now required
    __builtin_amdgcn_s_barrier();
  }

  // epilogue: scatter q, k, vT
#pragma unroll
  for (int mi = 0; mi < 4; mi++) {
#pragma unroll
    for (int ni = 0; ni < 6; ni++) {
#pragma unroll
      for (int r = 0; r < 4; r++) {
        int m = by * 128 + wm + (mi & 1) * 16 + (mi >> 1) * 32 + fq * 4 + r;
        int n = bx * 192 + wn + ni * 16 + fr;
        u16 hv = f2bf(acc[mi][ni][r]);
        int seg = n >> 10, cn = n & 1023;
        int b = m >> 11, tt = m & 2047;
        if (seg == 0)
          qO[(((size_t)(b * Tt + tt)) << 10) + cn] = hv;
        else if (seg == 1)
          kO[(((size_t)(b * Tt + tt)) << 10) + cn] = hv;
        else
          vTO[((size_t)(b * Cc + cn)) * Tt + tt] = hv;
      }
    }
  }
}

// ---- 512-thread stage helper for the E kernel ----
__device__ __forceinline__ void stage_unit(const u16* __restrict__ G, int ld,
                                           u16* lds_unit, int tid) {
#pragma unroll
  for (int j = 0; j < 2; j++) {
    int u = j * 8192 + tid * 16;
    int l = u ^ (((u >> 7) & 7) << 4);
    GLOAD_LDS16(G + (size_t)(l >> 6) * ld + ((l & 63) >> 1), lds_unit + (u >> 1));
  }
}

// ============ 256x256 8-phase GEMM — fused score+exp (E = exp(q.k^T/32), rowsum) ============
__global__ __launch_bounds__(512, 2) void gemm256_e(
    const u16* __restrict__ A0, const u16* __restrict__ B0,
    size_t sAbatch, size_t sBbatch,
    u16* __restrict__ EO, float* __restrict__ rowsum) {
  const int lda = Cc, ldb = Cc, NT = Cc / 64;  // 16
  int bx = blockIdx.x, by = blockIdx.y, bz = blockIdx.z;
  if (bx > by) return;

  const u16* A = A0 + (size_t)bz * sAbatch + (size_t)by * 256 * lda;
  const u16* Bt = B0 + (size_t)bz * sBbatch + (size_t)bx * 256 * ldb;

  __shared__ __attribute__((aligned(16))) u16 lds[4][2][8192];  // 128 KiB

  int tid = threadIdx.x;
  int lane = tid & 63, w = tid >> 6;
  int wm = (w >> 2) * 128, wn = (w & 3) * 64;
  int fr = lane & 15, fq = lane >> 4;

  f32x4 acc[8][4] = {};

  stage_unit(A + 0, lda, &lds[0][0][0], tid);
  stage_unit(Bt + 0, ldb, &lds[2][0][0], tid);
  stage_unit(A + 32, lda, &lds[1][0][0], tid);
  stage_unit(Bt + 32, ldb, &lds[3][0][0], tid);
  stage_unit(A + 64, lda, &lds[0][1][0], tid);
  stage_unit(Bt + 64, ldb, &lds[2][1][0], tid);
  WAITV8;
  __builtin_amdgcn_s_barrier();

  for (int t = 0; t < NT; ++t) {
    int par = t & 1;
    int parn = par ^ 1;
    bool st1 = (t + 1 < NT);
    bool st2 = (t + 2 < NT);
    bool tail = (t >= NT - 2);
    bf16x8 a[4], b[4];

    // phase 1: (mh=0, kh=0)
#pragma unroll
    for (int mi = 0; mi < 4; mi++)
      a[mi] = lds_frag(&lds[0][par][0], wm + mi * 16 + fr, fq);
#pragma unroll
    for (int ni = 0; ni < 4; ni++)
      b[ni] = lds_frag(&lds[2][par][0], wn + ni * 16 + fr, fq);
    if (st1) stage_unit(A + (t + 1) * 64 + 32, lda, &lds[1][parn][0], tid);
    __builtin_amdgcn_s_barrier();
    __builtin_amdgcn_s_setprio(1);
#pragma unroll
    for (int mi = 0; mi < 4; mi++)
#pragma unroll
      for (int ni = 0; ni < 4; ni++)
        acc[mi][ni] = __builtin_amdgcn_mfma_f32_16x16x32_bf16(a[mi], b[ni], acc[mi][ni], 0, 0, 0);
    __builtin_amdgcn_s_setprio(0);
    __builtin_amdgcn_s_barrier();

    // phase 2: (mh=1, kh=0)
#pragma unroll
    for (int mi = 0; mi < 4; mi++)
      a[mi] = lds_frag(&lds[0][par][0], wm + 64 + mi * 16 + fr, fq);
    if (st1) stage_unit(Bt + (t + 1) * 64 + 32, ldb, &lds[3][parn][0], tid);
    __builtin_amdgcn_s_barrier();
    __builtin_amdgcn_s_setprio(1);
#pragma unroll
    for (int mi = 0; mi < 4; mi++)
#pragma unroll
      for (int ni = 0; ni < 4; ni++)
        acc[4 + mi][ni] = __builtin_amdgcn_mfma_f32_16x16x32_bf16(a[mi], b[ni], acc[4 + mi][ni], 0, 0, 0);
    __builtin_amdgcn_s_setprio(0);
    if (tail) { WAITV0; } else { WAITV8; }
    __builtin_amdgcn_s_barrier();

    // phase 3: (mh=0, kh=1)
#pragma unroll
    for (int mi = 0; mi < 4; mi++)
      a[mi] = lds_frag(&lds[1][par][0], wm + mi * 16 + fr, fq);
#pragma unroll
    for (int ni = 0; ni < 4; ni++)
      b[ni] = lds_frag(&lds[3][par][0], wn + ni * 16 + fr, fq);
    if (st2) stage_unit(A + (t + 2) * 64, lda, &lds[0][par][0], tid);
    __builtin_amdgcn_s_barrier();
    __builtin_amdgcn_s_setprio(1);
#pragma unroll
    for (int mi = 0; mi < 4; mi++)
#pragma unroll
      for (int ni = 0; ni < 4; ni++)
        acc[mi][ni] = __builtin_amdgcn_mfma_f32_16x16x32_bf16(a[mi], b[ni], acc[mi][ni], 0, 0, 0);
    __builtin_amdgcn_s_setprio(0);
    __builtin_amdgcn_s_barrier();

    // phase 4: (mh=1, kh=1)
#pragma unroll
    for (int mi = 0; mi < 4; mi++)
      a[mi] = lds_frag(&lds[1][par][0], wm + 64 + mi * 16 + fr, fq);
    if (st2) stage_unit(Bt + (t + 2) * 64, ldb, &lds[2][par][0], tid);
    __builtin_amdgcn_s_barrier();
    __builtin_amdgcn_s_setprio(1);
#pragma unroll
    for (int mi = 0; mi < 4; mi++)
#pragma unroll
      for (int ni = 0; ni < 4; ni++)
        acc[4 + mi][ni] = __builtin_amdgcn_mfma_f32_16x16x32_bf16(a[mi], b[ni], acc[4 + mi][ni], 0, 0, 0);
    __builtin_amdgcn_s_setprio(0);
    if (tail) { WAITV0; } else { WAITV8; }
    __builtin_amdgcn_s_barrier();
  }

  // epilogue: fused exp + causal mask + bf16 E write + per-row partial sums
  {
    float rpart[8][4];
#pragma unroll
    for (int mi = 0; mi < 8; mi++)
#pragma unroll
      for (int r = 0; r < 4; r++) rpart[mi][r] = 0.f;
#pragma unroll
    for (int mi = 0; mi < 8; mi++) {
#pragma unroll
      for (int ni = 0; ni < 4; ni++) {
#pragma unroll
        for (int r = 0; r < 4; r++) {
          int m = by * 256 + wm + mi * 16 + fq * 4 + r;
          int n = bx * 256 + wn + ni * 16 + fr;
          float e = 0.f;
          if (n <= m) e = __expf(fminf(acc[mi][ni][r] * 0.03125f, 30.f));
          EO[((size_t)bz * Tt + m) * Tt + n] = f2bf(e);
          rpart[mi][r] += e;
        }
      }
    }
#pragma unroll
    for (int mi = 0; mi < 8; mi++) {
#pragma unroll
      for (int r = 0; r < 4; r++) {
        float v = rpart[mi][r];
        v += __shfl_xor(v, 1);
        v += __shfl_xor(v, 2);
        v += __shfl_xor(v, 4);
        v += __shfl_xor(v, 8);
        if (fr == 0) {
          int m = by * 256 + wm + mi * 16 + fq * 4 + r;
          atomicAdd(&rowsum[(size_t)bz * Tt + m], v);
        }
      }
    }
  }
}

// ---------------- m97-structure B^T MFMA GEMM, 128x128 tile, 4 waves ----------------
// Y = E.vT / rowsum (fp32 out), causal K truncation
__global__ __launch_bounds__(256) void gemm_bt_pv(
    const u16* __restrict__ A0, const u16* __restrict__ B0,
    size_t sAbatch, size_t sBbatch,
    int K, int lda, int ldb, const float* __restrict__ rowsum,
    float* __restrict__ YO) {
  int bx = blockIdx.x, by = blockIdx.y, bz = blockIdx.z;

  const u16* A = A0 + (size_t)bz * sAbatch + (size_t)by * 128 * lda;
  const u16* Bt = B0 + (size_t)bz * sBbatch + (size_t)bx * 128 * ldb;
  int kEnd = min(K, (by + 1) * 128);

  __shared__ __attribute__((aligned(16))) u16 As[128 * 32];
  __shared__ __attribute__((aligned(16))) u16 Bs[128 * 32];

  int tid = threadIdx.x;
  int lane = tid & 63, w = tid >> 6;
  int wr = (w >> 1) * 64, wc = (w & 1) * 64;
  int row16 = lane & 15, kq = (lane >> 4) * 8;

  int r0 = w * 16 + (lane >> 2);
  int c0 = (lane & 3) * 8;

  f32x4 acc[4][4] = {};

  for (int kt = 0; kt < kEnd; kt += 32) {
    const u16* Ag = A + (size_t)r0 * lda + kt + c0;
    const u16* Bg = Bt + (size_t)r0 * ldb + kt + c0;
    GLOAD_LDS16(Ag, &As[w * 512]);
    GLOAD_LDS16(Ag + (size_t)64 * lda, &As[2048 + w * 512]);
    GLOAD_LDS16(Bg, &Bs[w * 512]);
    GLOAD_LDS16(Bg + (size_t)64 * ldb, &Bs[2048 + w * 512]);
    __syncthreads();

    bf16x8 a[4], b[4];
#pragma unroll
    for (int m = 0; m < 4; m++)
      a[m] = *reinterpret_cast<const bf16x8*>(&As[(wr + m * 16 + row16) * 32 + kq]);
#pragma unroll
    for (int n = 0; n < 4; n++)
      b[n] = *reinterpret_cast<const bf16x8*>(&Bs[(wc + n * 16 + row16) * 32 + kq]);
#pragma unroll
    for (int m = 0; m < 4; m++)
#pragma unroll
      for (int n = 0; n < 4; n++)
        acc[m][n] = __builtin_amdgcn_mfma_f32_16x16x32_bf16(a[m], b[n], acc[m][n], 0, 0, 0);
    __syncthreads();
  }

  int colf = lane & 15, rbase = (lane >> 4) * 4;
#pragma unroll
  for (int i = 0; i < 4; i++) {
#pragma unroll
    for (int r = 0; r < 4; r++) {
      int m = by * 128 + wr + i * 16 + rbase + r;
      float inv = 1.0f / rowsum[(size_t)bz * Tt + m];
#pragma unroll
      for (int j = 0; j < 4; j++) {
        int n = bx * 128 + wc + j * 16 + colf;
        YO[((size_t)bz * Tt + m) * Cc + n] = acc[i][j][r] * inv;
      }
    }
  }
}

extern "C" void kernel_launch(void* const* d_in, const int* in_sizes, int n_in,
                              void* d_out, int out_size, void* d_ws, size_t ws_size,
                              hipStream_t stream) {
  const float* x = (const float*)d_in[0];
  const float* W = (const float*)d_in[1];
  float* Y = (float*)d_out;

  char* ws = (char*)d_ws;
  size_t off = 0;
  auto carve = [&](size_t bytes) -> void* {
    void* p = ws + off;
    off += (bytes + 255) & ~(size_t)255;
    return p;
  };
  u16* xb = (u16*)carve((size_t)Bb * Tt * Cc * 2);
  u16* wt = (u16*)carve((size_t)3 * Cc * Cc * 2);
  u16* qb = (u16*)carve((size_t)Bb * Tt * Cc * 2);
  u16* kb = (u16*)carve((size_t)Bb * Tt * Cc * 2);
  u16* vT = (u16*)carve((size_t)Bb * Cc * Tt * 2);
  u16* E = (u16*)carve((size_t)Bb * Tt * Tt * 2);   // exp(scores) bf16
  float* rowsum = (float*)carve((size_t)Bb * Tt * 4);

  cast_f32_bf16_vec4<<<(Bb * Tt * Cc / 4 + 255) / 256, 256, 0, stream>>>(
      x, xb, Bb * Tt * Cc / 4);
  zero_f32<<<(Bb * Tt + 255) / 256, 256, 0, stream>>>(rowsum, Bb * Tt);
  transpose_cast_w<<<dim3(96, 32), dim3(32, 8), 0, stream>>>(W, wt);
  // qkv projection: 128x192 tiles, 8-phase, 2 blocks/CU, 2 balanced rounds
  gemm_qkv_128x192<<<dim3(16, 64), 256, 0, stream>>>(xb, wt, qb, kb, vT);
  // E = exp(q k^T / 32) + rowsum: 256^2 8-phase, causal tri-grid
  gemm256_e<<<dim3(8, 8, 4), 512, 0, stream>>>(
      qb, kb, (size_t)Tt * Cc, (size_t)Tt * Cc, E, rowsum);
  // Y = (E v) / rowsum (causal K truncation), 128^2 m97 structure
  gemm_bt_pv<<<dim3(8, 16, 4), 256, 0, stream>>>(
      E, vT, (size_t)Tt * Tt, (size_t)Cc * Tt, Tt, Tt, Tt, rowsum, Y);
}